// Round 5
// baseline (952.575 us; speedup 1.0000x reference)
//
#include <hip/hip_runtime.h>
#include <hip/hip_bf16.h>

#define B_N 16384
#define D_DIM 1024
#define NGRP 64
#define NCHUNK 64
#define CHUNK 256

typedef __attribute__((ext_vector_type(8))) short short8;
typedef __attribute__((ext_vector_type(8))) unsigned short ushort8;
typedef __attribute__((ext_vector_type(4))) unsigned short ushort4v;
typedef __attribute__((ext_vector_type(4))) float floatx4;

__device__ __forceinline__ float bf2f(unsigned short h) {
    union { unsigned u; float f; } c; c.u = ((unsigned)h) << 16; return c.f;
}
__device__ __forceinline__ unsigned short f2bf(float f) {
    union { float f; unsigned u; } c; c.f = f;
    unsigned r = c.u + 0x7FFFu + ((c.u >> 16) & 1u);
    return (unsigned short)(r >> 16);
}

__device__ __forceinline__ void gload_lds16(const void* g, void* l) {
    __builtin_amdgcn_global_load_lds(
        (const __attribute__((address_space(1))) unsigned int*)g,
        (__attribute__((address_space(3))) unsigned int*)l, 16, 0, 0);
}

// ---------- stable counting sort ----------
__global__ __launch_bounds__(256) void k_hist(const int* __restrict__ labels,
                                              int* __restrict__ hist) {
    __shared__ int lh[NGRP];
    int t = threadIdx.x, c = blockIdx.x;
    if (t < NGRP) lh[t] = 0;
    __syncthreads();
    int lab = labels[c * CHUNK + t];
    atomicAdd(&lh[lab], 1);
    __syncthreads();
    if (t < NGRP) hist[c * NGRP + t] = lh[t];
}

__global__ void k_scan(int* __restrict__ hist, int* __restrict__ gstart,
                       int* __restrict__ counts, float* __restrict__ scal) {
    __shared__ int cnt[NGRP];
    __shared__ int st[NGRP + 1];
    int g = threadIdx.x;
    int run = 0;
    for (int c = 0; c < NCHUNK; c++) {
        int v = hist[c * NGRP + g];
        hist[c * NGRP + g] = run;
        run += v;
    }
    cnt[g] = run;
    counts[g] = run;
    __syncthreads();
    if (g == 0) {
        int s = 0, np = 0;
        for (int i = 0; i < NGRP; i++) { st[i] = s; s += cnt[i]; np += (cnt[i] > 0); }
        st[NGRP] = s;
        scal[0] = (np > 1) ? 1.0f / (float)(np - 1) : 0.0f;
    }
    __syncthreads();
    gstart[g] = st[g];
    if (g == 0) gstart[NGRP] = st[NGRP];
    for (int c = 0; c < NCHUNK; c++) hist[c * NGRP + g] += st[g];
}

__global__ __launch_bounds__(256) void k_scatter(const int* __restrict__ labels,
                                                 const int* __restrict__ hist,
                                                 int* __restrict__ perm,
                                                 int* __restrict__ ls) {
    __shared__ int lab[CHUNK];
    int c = blockIdx.x, t = threadIdx.x;
    int i = c * CHUNK + t;
    int L = labels[i];
    lab[t] = L;
    __syncthreads();
    int rank = 0;
    for (int j = 0; j < t; j++) rank += (lab[j] == L);
    int pos = hist[c * NGRP + L] + rank;
    perm[pos] = i;
    ls[pos] = L;
}

// ---------- segment conv -> tok INTERLEAVED (row 2i = t2_i, row 2i+1 = t4_i) ----------
__global__ __launch_bounds__(256) void k_conv(const float* __restrict__ x,
                                              const int* __restrict__ perm,
                                              const int* __restrict__ ls,
                                              const float* __restrict__ w2, const float* __restrict__ b2,
                                              const float* __restrict__ w4, const float* __restrict__ b4,
                                              unsigned short* __restrict__ tok) {
    const int i = blockIdx.x;
    const int li = ls[i];
    const int p0 = perm[i];
    const int pm1 = (i >= 1 && ls[i - 1] == li) ? perm[i - 1] : -1;
    const int pm2 = (i >= 2 && ls[i - 2] == li) ? perm[i - 2] : -1;
    const int pp1 = (i + 1 < B_N && ls[i + 1] == li) ? perm[i + 1] : -1;
    const int c = threadIdx.x * 4;
    floatx4 z = (floatx4)0.0f;
    floatx4 x0 = *(const floatx4*)(x + (size_t)p0 * D_DIM + c);
    floatx4 xm1 = (pm1 >= 0) ? *(const floatx4*)(x + (size_t)pm1 * D_DIM + c) : z;
    floatx4 xm2 = (pm2 >= 0) ? *(const floatx4*)(x + (size_t)pm2 * D_DIM + c) : z;
    floatx4 xp1 = (pp1 >= 0) ? *(const floatx4*)(x + (size_t)pp1 * D_DIM + c) : z;
    const float w20 = w2[0], w21 = w2[1], cb2 = b2[0];
    const float w40 = w4[0], w41 = w4[1], w42 = w4[2], w43 = w4[3], cb4 = b4[0];
    ushort4v o2, o4;
#pragma unroll
    for (int j = 0; j < 4; j++) {
        float t2 = w20 * xm1[j] + w21 * x0[j] + cb2;
        float t4 = w40 * xm2[j] + w41 * xm1[j] + w42 * x0[j] + w43 * xp1[j] + cb4;
        o2[j] = f2bf(t2);
        o4[j] = f2bf(t4);
    }
    *(ushort4v*)(tok + (size_t)(2 * i) * D_DIM + c) = o2;
    *(ushort4v*)(tok + (size_t)(2 * i + 1) * D_DIM + c) = o4;
}

// ---------- fused weight prep: cast Wqk (2M), linwb (1M); transpose-cast WoT, WvT ----------
__global__ __launch_bounds__(256) void k_prep(const float* __restrict__ intra_in_w,
                                              const float* __restrict__ lin_w,
                                              const float* __restrict__ intra_out_w,
                                              unsigned short* __restrict__ Wqk,
                                              unsigned short* __restrict__ linwb,
                                              unsigned short* __restrict__ WoT,
                                              unsigned short* __restrict__ WvT) {
    __shared__ float tile[32][33];
    const int bx = blockIdx.x;
    if (bx < 3072) {
        int i = bx * 256 + threadIdx.x;
        const float* src;
        unsigned short* dst;
        int j;
        if (i < 524288) { src = intra_in_w; dst = Wqk; j = i; }
        else { src = lin_w; dst = linwb; j = i - 524288; }
        floatx4 v = *(const floatx4*)(src + (size_t)j * 4);
        ushort4v o;
#pragma unroll
        for (int q = 0; q < 4; q++) o[q] = f2bf(v[q]);
        *(ushort4v*)(dst + (size_t)j * 4) = o;
    } else {
        int tb = bx - 3072;
        const float* src;
        unsigned short* dst;
        if (tb < 1024) { src = intra_out_w; dst = WoT; }
        else { src = intra_in_w + (size_t)2048 * D_DIM; dst = WvT; tb -= 1024; }
        const int bX = (tb & 31) * 32, bY = (tb >> 5) * 32;
        const int tx = threadIdx.x & 31, ty = threadIdx.x >> 5;
        for (int r = ty; r < 32; r += 8)
            tile[r][tx] = src[(size_t)(bY + r) * D_DIM + bX + tx];
        __syncthreads();
        for (int r = ty; r < 32; r += 8)
            dst[(size_t)(bX + r) * D_DIM + bY + tx] = f2bf(tile[tx][r]);
    }
}

// ---------- ob2 = intra_out_b + Wo @ bv  (folds v-bias through out-proj) ----------
__global__ __launch_bounds__(256) void k_ob2(const float* __restrict__ ow,
                                             const float* __restrict__ ob,
                                             const float* __restrict__ bv,
                                             float* __restrict__ ob2) {
    int e = blockIdx.x * 256 + threadIdx.x;
    const floatx4* wr4 = (const floatx4*)(ow + (size_t)e * D_DIM);
    const floatx4* bv4 = (const floatx4*)bv;
    float s = ob[e];
    for (int k4 = 0; k4 < D_DIM / 4; k4++) {
        floatx4 a = wr4[k4], b = bv4[k4];
        s += a[0] * b[0] + a[1] * b[1] + a[2] * b[2] + a[3] * b[3];
    }
    ob2[e] = s;
}

// ---------- inter path (fp32, tiny); blockIdx.y==NGRP computes biasc ----------
__global__ __launch_bounds__(256) void k_u(const float* __restrict__ x,
                                           const int* __restrict__ perm,
                                           const int* __restrict__ gstart,
                                           const int* __restrict__ counts,
                                           const float* __restrict__ Wfull,
                                           const float* __restrict__ bfull,
                                           float* __restrict__ u,
                                           const float* __restrict__ lin_w,
                                           const float* __restrict__ lin_b,
                                           const float* __restrict__ ob2,
                                           float* __restrict__ biasc) {
    const int g = blockIdx.y;
    const int n = blockIdx.x * 256 + threadIdx.x;
    __shared__ __align__(16) float xr[D_DIM];
    const bool isb = (g == NGRP);
    int row = 0;
    if (!isb) {
        const int cnt = counts[g];
        row = (cnt > 0) ? perm[gstart[g]] : 0;
    }
    for (int k = threadIdx.x; k < D_DIM; k += 256)
        xr[k] = isb ? ob2[k] : x[(size_t)row * D_DIM + k];
    __syncthreads();
    const float* wrow = isb ? (lin_w + (size_t)n * D_DIM)
                            : (Wfull + (size_t)(2 * D_DIM + n) * D_DIM);
    const floatx4* wr4 = (const floatx4*)wrow;
    const floatx4* xr4 = (const floatx4*)xr;
    float s = isb ? lin_b[n] : bfull[2 * D_DIM + n];
    for (int k4 = 0; k4 < D_DIM / 4; k4++) {
        floatx4 a = xr4[k4], b = wr4[k4];
        s += a[0] * b[0] + a[1] * b[1] + a[2] * b[2] + a[3] * b[3];
    }
    if (isb) biasc[n] = s;
    else u[g * D_DIM + n] = s;
}

__global__ __launch_bounds__(256) void k_f(const float* __restrict__ u,
                                           const int* __restrict__ counts,
                                           const float* __restrict__ W,
                                           const float* __restrict__ b,
                                           float* __restrict__ f) {
    const int g = blockIdx.y;
    const int n = blockIdx.x * 256 + threadIdx.x;
    __shared__ __align__(16) float ur[D_DIM];
    const int cnt = counts[g];
    for (int k = threadIdx.x; k < D_DIM; k += 256) ur[k] = u[g * D_DIM + k];
    __syncthreads();
    const floatx4* wr4 = (const floatx4*)(W + (size_t)n * D_DIM);
    const floatx4* ur4 = (const floatx4*)ur;
    float s = b[n];
    for (int k4 = 0; k4 < D_DIM / 4; k4++) {
        floatx4 a = ur4[k4], w = wr4[k4];
        s += a[0] * w[0] + a[1] * w[1] + a[2] * w[2] + a[3] * w[3];
    }
    f[g * D_DIM + n] = (cnt > 0) ? s : 0.0f;
}

__global__ __launch_bounds__(256) void k_imean(const float* __restrict__ f,
                                               const float* __restrict__ scal,
                                               float* __restrict__ im) {
    int c = blockIdx.x * 256 + threadIdx.x;
    float s = 0.0f;
    for (int g = 0; g < NGRP; g++) s += f[g * D_DIM + c];
    float fl = scal[0];
    for (int g = 0; g < NGRP; g++) im[g * D_DIM + c] = (s - f[g * D_DIM + c]) * fl;
}

__global__ __launch_bounds__(256) void k_zero(float* __restrict__ p) {
    ((floatx4*)p)[blockIdx.x * 256 + threadIdx.x] = (floatx4)0.0f;
}

// ---------- bf16 MFMA GEMM: C[m][n] = sum_k A[m][k']*W[n][k'] with lda/ldw ----------
// MODE 1: outb[m*ldc + n] = bf16(acc)
// MODE 2: outf[perm[m]][n] = acc + bias[n] + imean[ls[m]][n]   (final, scattered)
template <int MODE>
__global__ __launch_bounds__(256)
void gemm_bt(const unsigned short* __restrict__ A,
             const unsigned short* __restrict__ W,
             int M, int N, int K, int lda, int ldw,
             const float* __restrict__ bias,
             unsigned short* __restrict__ outb, int ldc,
             float* __restrict__ outf,
             const int* __restrict__ perm,
             const int* __restrict__ ls,
             const float* __restrict__ imean) {
    __shared__ __align__(16) unsigned short sA[128 * 64];
    __shared__ __align__(16) unsigned short sB[128 * 64];
    const int t = threadIdx.x;
    const int lane = t & 63, wv = t >> 6;
    int bx = blockIdx.x, by = blockIdx.y;
    const int nX = gridDim.x, nY = gridDim.y;
    if ((nY & 7) == 0) {
        const int bid = by * nX + bx;
        const int xcd = bid & 7, j = bid >> 3;
        const int stripe = nY >> 3;
        by = xcd * stripe + j / nX;
        bx = j % nX;
    }
    const int m0 = by * 128, n0 = bx * 128;
    const int wm = (wv & 1) * 64, wn = (wv >> 1) * 64;
    const int l15 = lane & 15, quad = lane >> 4;
    const int sw = l15 & 7;

    floatx4 acc[4][4];
#pragma unroll
    for (int i = 0; i < 4; i++)
#pragma unroll
        for (int j = 0; j < 4; j++) acc[i][j] = (floatx4)0.0f;

    for (int k0 = 0; k0 < K; k0 += 64) {
#pragma unroll
        for (int r = 0; r < 4; r++) {
            const int chunk = r * 256 + wv * 64;
            const int idx = chunk + lane;
            const int row = idx >> 3;
            const int kb = (idx & 7) ^ (row & 7);
            gload_lds16(A + (size_t)(m0 + row) * lda + k0 + kb * 8, &sA[chunk * 8]);
            gload_lds16(W + (size_t)(n0 + row) * ldw + k0 + kb * 8, &sB[chunk * 8]);
        }
        __syncthreads();
#pragma unroll
        for (int kk = 0; kk < 64; kk += 32) {
            const int kc = kk >> 3;
            short8 av[4], bv[4];
#pragma unroll
            for (int mt = 0; mt < 4; mt++)
                av[mt] = *(const short8*)&sA[(wm + mt * 16 + l15) * 64 +
                                             (((kc + quad) ^ sw) << 3)];
#pragma unroll
            for (int nt = 0; nt < 4; nt++)
                bv[nt] = *(const short8*)&sB[(wn + nt * 16 + l15) * 64 +
                                             (((kc + quad) ^ sw) << 3)];
#pragma unroll
            for (int mt = 0; mt < 4; mt++)
#pragma unroll
                for (int nt = 0; nt < 4; nt++)
                    acc[mt][nt] = __builtin_amdgcn_mfma_f32_16x16x32_bf16(
                        av[mt], bv[nt], acc[mt][nt], 0, 0, 0);
        }
        __syncthreads();
    }

    if (MODE == 1) {
#pragma unroll
        for (int nt = 0; nt < 4; nt++) {
            const int gc = n0 + wn + nt * 16 + l15;
#pragma unroll
            for (int mt = 0; mt < 4; mt++) {
                const int gr = m0 + wm + mt * 16 + quad * 4;
#pragma unroll
                for (int r = 0; r < 4; r++)
                    outb[(size_t)(gr + r) * ldc + gc] = f2bf(acc[mt][nt][r]);
            }
        }
    } else {
        float bb[4];
        int gc4[4];
#pragma unroll
        for (int nt = 0; nt < 4; nt++) {
            gc4[nt] = n0 + wn + nt * 16 + l15;
            bb[nt] = bias[gc4[nt]];
        }
#pragma unroll
        for (int mt = 0; mt < 4; mt++) {
#pragma unroll
            for (int r = 0; r < 4; r++) {
                const int i = m0 + wm + mt * 16 + quad * 4 + r;
                const int orow = perm[i];
                const int lg = ls[i];
#pragma unroll
                for (int nt = 0; nt < 4; nt++)
                    outf[(size_t)orow * N + gc4[nt]] =
                        acc[mt][nt][r] + bb[nt] + imean[lg * D_DIM + gc4[nt]];
            }
        }
    }
}

// ---------- fused q/k projection + score partials (never materializes q,k) ----------
// A = interleaved tok [2*B_N][1024]; block = 128 rows x 64 q-cols; dual B (Wq, Wk).
// Epilogue: per pair (rows 2i,2i+1) partial dots q·k over this block's 64 cols,
// lane-reduced, atomicAdd into scores[i][head*4 + {s22,s24,s42,s44}].
__global__ __launch_bounds__(256) void k_qkscore(const unsigned short* __restrict__ A,
                                                 const unsigned short* __restrict__ Wq,
                                                 const unsigned short* __restrict__ Wk,
                                                 const float* __restrict__ bq,
                                                 const float* __restrict__ bk,
                                                 float* __restrict__ scores) {
    __shared__ __align__(16) unsigned short sA[128 * 64];
    __shared__ __align__(16) unsigned short sBq[64 * 64];
    __shared__ __align__(16) unsigned short sBk[64 * 64];
    const int t = threadIdx.x;
    const int lane = t & 63, wv = t >> 6;
    int bx = blockIdx.x, by = blockIdx.y;  // (16, 256)
    {
        const int nX = gridDim.x, nY = gridDim.y;
        const int bid = by * nX + bx;
        const int xcd = bid & 7, j = bid >> 3;
        const int stripe = nY >> 3;
        by = xcd * stripe + j / nX;
        bx = j % nX;
    }
    const int m0 = by * 128, n0 = bx * 64;
    const int wm = (wv & 1) * 64, wn = (wv >> 1) * 32;
    const int l15 = lane & 15, quad = lane >> 4;
    const int sw = l15 & 7;

    floatx4 qa[4][2], ka[4][2];
#pragma unroll
    for (int i = 0; i < 4; i++)
#pragma unroll
        for (int j = 0; j < 2; j++) { qa[i][j] = (floatx4)0.0f; ka[i][j] = (floatx4)0.0f; }

    for (int k0 = 0; k0 < D_DIM; k0 += 64) {
#pragma unroll
        for (int r = 0; r < 4; r++) {
            const int chunk = r * 256 + wv * 64;
            const int idx = chunk + lane;
            const int row = idx >> 3;
            const int kb = (idx & 7) ^ (row & 7);
            gload_lds16(A + (size_t)(m0 + row) * D_DIM + k0 + kb * 8, &sA[chunk * 8]);
        }
#pragma unroll
        for (int r = 0; r < 2; r++) {
            const int chunk = r * 256 + wv * 64;
            const int idx = chunk + lane;
            const int row = idx >> 3;  // 0..63
            const int kb = (idx & 7) ^ (row & 7);
            gload_lds16(Wq + (size_t)(n0 + row) * D_DIM + k0 + kb * 8, &sBq[chunk * 8]);
            gload_lds16(Wk + (size_t)(n0 + row) * D_DIM + k0 + kb * 8, &sBk[chunk * 8]);
        }
        __syncthreads();
#pragma unroll
        for (int kk = 0; kk < 64; kk += 32) {
            const int kc = kk >> 3;
            short8 av[4], bqv[2], bkv[2];
#pragma unroll
            for (int mt = 0; mt < 4; mt++)
                av[mt] = *(const short8*)&sA[(wm + mt * 16 + l15) * 64 +
                                             (((kc + quad) ^ sw) << 3)];
#pragma unroll
            for (int nt = 0; nt < 2; nt++) {
                bqv[nt] = *(const short8*)&sBq[(wn + nt * 16 + l15) * 64 +
                                               (((kc + quad) ^ sw) << 3)];
                bkv[nt] = *(const short8*)&sBk[(wn + nt * 16 + l15) * 64 +
                                               (((kc + quad) ^ sw) << 3)];
            }
#pragma unroll
            for (int mt = 0; mt < 4; mt++)
#pragma unroll
                for (int nt = 0; nt < 2; nt++) {
                    qa[mt][nt] = __builtin_amdgcn_mfma_f32_16x16x32_bf16(
                        av[mt], bqv[nt], qa[mt][nt], 0, 0, 0);
                    ka[mt][nt] = __builtin_amdgcn_mfma_f32_16x16x32_bf16(
                        av[mt], bkv[nt], ka[mt][nt], 0, 0, 0);
                }
        }
        __syncthreads();
    }

    const int head = n0 >> 9;
    float bqv2[2], bkv2[2];
#pragma unroll
    for (int nt = 0; nt < 2; nt++) {
        const int col = n0 + wn + nt * 16 + l15;
        bqv2[nt] = bq[col];
        bkv2[nt] = bk[col];
    }
#pragma unroll
    for (int mt = 0; mt < 4; mt++) {
#pragma unroll
        for (int p = 0; p < 2; p++) {
            float s22 = 0, s24 = 0, s42 = 0, s44 = 0;
#pragma unroll
            for (int nt = 0; nt < 2; nt++) {
                float q0 = qa[mt][nt][2 * p] + bqv2[nt];
                float q1 = qa[mt][nt][2 * p + 1] + bqv2[nt];
                float k0v = ka[mt][nt][2 * p] + bkv2[nt];
                float k1v = ka[mt][nt][2 * p + 1] + bkv2[nt];
                s22 += q0 * k0v; s24 += q0 * k1v; s42 += q1 * k0v; s44 += q1 * k1v;
            }
#pragma unroll
            for (int d = 1; d < 16; d <<= 1) {
                s22 += __shfl_xor(s22, d, 64);
                s24 += __shfl_xor(s24, d, 64);
                s42 += __shfl_xor(s42, d, 64);
                s44 += __shfl_xor(s44, d, 64);
            }
            if (l15 == 0) {
                const int i = (m0 + wm + mt * 16 + quad * 4 + 2 * p) >> 1;
                atomicAdd(&scores[i * 8 + head * 4 + 0], s22);
                atomicAdd(&scores[i * 8 + head * 4 + 1], s24);
                atomicAdd(&scores[i * 8 + head * 4 + 2], s42);
                atomicAdd(&scores[i * 8 + head * 4 + 3], s44);
            }
        }
    }
}

// ---------- scores -> gamma (softmax + mean over seq) ----------
__global__ __launch_bounds__(256) void k_gam(const float* __restrict__ scores,
                                             floatx4* __restrict__ gam) {
    const int i = blockIdx.x * 256 + threadIdx.x;
    const float sc = 0.044194173824159216f;  // 1/sqrt(512)
    floatx4 g;
#pragma unroll
    for (int h = 0; h < 2; h++) {
        float s22 = scores[i * 8 + h * 4 + 0] * sc;
        float s24 = scores[i * 8 + h * 4 + 1] * sc;
        float s42 = scores[i * 8 + h * 4 + 2] * sc;
        float s44 = scores[i * 8 + h * 4 + 3] * sc;
        float m0 = fmaxf(s22, s24), e22 = __expf(s22 - m0), e24 = __expf(s24 - m0);
        float w24 = e24 / (e22 + e24), w22 = 1.0f - w24;
        float m1 = fmaxf(s42, s44), e42 = __expf(s42 - m1), e44 = __expf(s44 - m1);
        float w44 = e44 / (e42 + e44), w42 = 1.0f - w44;
        g[h * 2 + 0] = 0.5f * (w22 + w42);
        g[h * 2 + 1] = 0.5f * (w24 + w44);
    }
    gam[i] = g;
}

// ---------- in-place gamma-combine: rows (2i,2i+1) of tok become [z1|z2] ----------
__global__ __launch_bounds__(256) void k_zprep(unsigned short* __restrict__ tok,
                                               const floatx4* __restrict__ gam) {
    const int idx = blockIdx.x * 256 + threadIdx.x;  // B_N*128 threads
    const int i = idx >> 7;
    const int seg = (idx & 127) * 8;
    floatx4 g = gam[i];
    short8 a = *(const short8*)(tok + (size_t)(2 * i) * D_DIM + seg);
    short8 b = *(const short8*)(tok + (size_t)(2 * i + 1) * D_DIM + seg);
    ushort8 z1, z2;
#pragma unroll
    for (int j = 0; j < 8; j++) {
        float af = bf2f((unsigned short)a[j]), bf = bf2f((unsigned short)b[j]);
        z1[j] = f2bf(g[0] * af + g[1] * bf);
        z2[j] = f2bf(g[2] * af + g[3] * bf);
    }
    *(ushort8*)(tok + (size_t)(2 * i) * D_DIM + seg) = z1;
    *(ushort8*)(tok + (size_t)(2 * i + 1) * D_DIM + seg) = z2;
}

extern "C" void kernel_launch(void* const* d_in, const int* in_sizes, int n_in,
                              void* d_out, int out_size, void* d_ws, size_t ws_size,
                              hipStream_t stream) {
    const float* x = (const float*)d_in[0];
    const int* labels = (const int*)d_in[1];
    const float* conv_w2 = (const float*)d_in[3];
    const float* conv_b2 = (const float*)d_in[4];
    const float* conv_w4 = (const float*)d_in[5];
    const float* conv_b4 = (const float*)d_in[6];
    const float* intra_in_w = (const float*)d_in[7];
    const float* intra_in_b = (const float*)d_in[8];
    const float* intra_out_w = (const float*)d_in[9];
    const float* intra_out_b = (const float*)d_in[10];
    const float* inter_in_w = (const float*)d_in[11];
    const float* inter_in_b = (const float*)d_in[12];
    const float* inter_out_w = (const float*)d_in[13];
    const float* inter_out_b = (const float*)d_in[14];
    const float* lin_w = (const float*)d_in[15];
    const float* lin_b = (const float*)d_in[16];
    float* out = (float*)d_out;

    char* p = (char*)d_ws;
    auto alloc = [&](size_t bytes) -> void* {
        void* r = (void*)p;
        p += (bytes + 255) & ~(size_t)255;
        return r;
    };
    int* perm = (int*)alloc(B_N * 4);
    int* lss = (int*)alloc(B_N * 4);
    int* hist = (int*)alloc(NCHUNK * NGRP * 4);
    int* gstart = (int*)alloc((NGRP + 1) * 4);
    int* counts = (int*)alloc(NGRP * 4);
    float* scal = (float*)alloc(4);
    unsigned short* tok = (unsigned short*)alloc((size_t)2 * B_N * D_DIM * 2);   // 64 MB
    unsigned short* Wqk = (unsigned short*)alloc((size_t)2 * D_DIM * D_DIM * 2); // 4 MB
    unsigned short* linwb = (unsigned short*)alloc((size_t)D_DIM * D_DIM * 2);
    unsigned short* WoT = (unsigned short*)alloc((size_t)D_DIM * D_DIM * 2);
    unsigned short* WvT = (unsigned short*)alloc((size_t)D_DIM * D_DIM * 2);
    unsigned short* Wc = (unsigned short*)alloc((size_t)D_DIM * D_DIM * 2);
    unsigned short* GG = (unsigned short*)alloc((size_t)D_DIM * 2 * D_DIM * 2);  // 4 MB
    float* scores = (float*)alloc((size_t)B_N * 8 * 4);
    floatx4* gam = (floatx4*)alloc((size_t)B_N * 16);
    float* u = (float*)alloc((size_t)NGRP * D_DIM * 4);
    float* fbuf = (float*)alloc((size_t)NGRP * D_DIM * 4);
    float* imean = (float*)alloc((size_t)NGRP * D_DIM * 4);
    float* biasc = (float*)alloc(D_DIM * 4);
    float* ob2 = (float*)alloc(D_DIM * 4);

    // ---- sort ----
    k_hist<<<NCHUNK, CHUNK, 0, stream>>>(labels, hist);
    k_scan<<<1, NGRP, 0, stream>>>(hist, gstart, counts, scal);
    k_scatter<<<NCHUNK, CHUNK, 0, stream>>>(labels, hist, perm, lss);
    // ---- weight prep ----
    k_prep<<<3072 + 2048, 256, 0, stream>>>(intra_in_w, lin_w, intra_out_w, Wqk, linwb,
                                            WoT, WvT);
    gemm_bt<1><<<dim3(8, 8), 256, 0, stream>>>(linwb, WoT, 1024, 1024, 1024, 1024, 1024,
                                               nullptr, Wc, 1024, nullptr, nullptr,
                                               nullptr, nullptr);
    // GG[n][h*1024+k] = sum_e Wc[n][h*512+e] * WvT[k][h*512+e]
    gemm_bt<1><<<dim3(8, 8), 256, 0, stream>>>(Wc, WvT, 1024, 1024, 512, 1024, 1024,
                                               nullptr, GG, 2048, nullptr, nullptr,
                                               nullptr, nullptr);
    gemm_bt<1><<<dim3(8, 8), 256, 0, stream>>>(Wc + 512, WvT + 512, 1024, 1024, 512, 1024,
                                               1024, nullptr, GG + 1024, 2048, nullptr,
                                               nullptr, nullptr, nullptr);
    k_ob2<<<4, 256, 0, stream>>>(intra_out_w, intra_out_b, intra_in_b + 2 * D_DIM, ob2);
    // ---- inter path (fp32) + biasc ----
    k_u<<<dim3(4, NGRP + 1), 256, 0, stream>>>(x, perm, gstart, counts, inter_in_w,
                                               inter_in_b, u, lin_w, lin_b, ob2, biasc);
    k_f<<<dim3(4, NGRP), 256, 0, stream>>>(u, counts, inter_out_w, inter_out_b, fbuf);
    k_imean<<<4, 256, 0, stream>>>(fbuf, scal, imean);
    // ---- conv -> interleaved tok ----
    k_conv<<<B_N, 256, 0, stream>>>(x, perm, lss, conv_w2, conv_b2, conv_w4, conv_b4, tok);
    // ---- fused qk + scores ----
    k_zero<<<B_N * 8 / 1024, 256, 0, stream>>>(scores);
    k_qkscore<<<dim3(16, 256), 256, 0, stream>>>(tok, Wqk, Wqk + (size_t)D_DIM * D_DIM,
                                                 intra_in_b, intra_in_b + D_DIM, scores);
    k_gam<<<B_N / 256, 256, 0, stream>>>(scores, gam);
    k_zprep<<<B_N / 2, 256, 0, stream>>>(tok, gam);
    // ---- merged v+out GEMM: out[perm[i]] = [z1|z2] . GG^T + biasc + imean ----
    gemm_bt<2><<<dim3(8, 128), 256, 0, stream>>>(tok, GG, B_N, 1024, 2048, 2048, 2048,
                                                 biasc, nullptr, 0, out, perm, lss, imean);
}

// Round 6
// 625.104 us; speedup vs baseline: 1.5239x; 1.5239x over previous
//
#include <hip/hip_runtime.h>
#include <hip/hip_bf16.h>

#define B_N 16384
#define D_DIM 1024
#define NGRP 64
#define NCHUNK 64
#define CHUNK 256

typedef __attribute__((ext_vector_type(8))) short short8;
typedef __attribute__((ext_vector_type(8))) unsigned short ushort8;
typedef __attribute__((ext_vector_type(4))) unsigned short ushort4v;
typedef __attribute__((ext_vector_type(4))) float floatx4;

__device__ __forceinline__ float bf2f(unsigned short h) {
    union { unsigned u; float f; } c; c.u = ((unsigned)h) << 16; return c.f;
}
__device__ __forceinline__ unsigned short f2bf(float f) {
    union { float f; unsigned u; } c; c.f = f;
    unsigned r = c.u + 0x7FFFu + ((c.u >> 16) & 1u);
    return (unsigned short)(r >> 16);
}

__device__ __forceinline__ void gload_lds16(const void* g, void* l) {
    __builtin_amdgcn_global_load_lds(
        (const __attribute__((address_space(1))) unsigned int*)g,
        (__attribute__((address_space(3))) unsigned int*)l, 16, 0, 0);
}

// ---------- stable counting sort ----------
__global__ __launch_bounds__(256) void k_hist(const int* __restrict__ labels,
                                              int* __restrict__ hist) {
    __shared__ int lh[NGRP];
    int t = threadIdx.x, c = blockIdx.x;
    if (t < NGRP) lh[t] = 0;
    __syncthreads();
    int lab = labels[c * CHUNK + t];
    atomicAdd(&lh[lab], 1);
    __syncthreads();
    if (t < NGRP) hist[c * NGRP + t] = lh[t];
}

__global__ void k_scan(int* __restrict__ hist, int* __restrict__ gstart,
                       int* __restrict__ counts, float* __restrict__ scal) {
    __shared__ int cnt[NGRP];
    __shared__ int st[NGRP + 1];
    int g = threadIdx.x;
    int run = 0;
    for (int c = 0; c < NCHUNK; c++) {
        int v = hist[c * NGRP + g];
        hist[c * NGRP + g] = run;
        run += v;
    }
    cnt[g] = run;
    counts[g] = run;
    __syncthreads();
    if (g == 0) {
        int s = 0, np = 0;
        for (int i = 0; i < NGRP; i++) { st[i] = s; s += cnt[i]; np += (cnt[i] > 0); }
        st[NGRP] = s;
        scal[0] = (np > 1) ? 1.0f / (float)(np - 1) : 0.0f;
    }
    __syncthreads();
    gstart[g] = st[g];
    if (g == 0) gstart[NGRP] = st[NGRP];
    for (int c = 0; c < NCHUNK; c++) hist[c * NGRP + g] += st[g];
}

__global__ __launch_bounds__(256) void k_scatter(const int* __restrict__ labels,
                                                 const int* __restrict__ hist,
                                                 int* __restrict__ perm,
                                                 int* __restrict__ ls) {
    __shared__ int lab[CHUNK];
    int c = blockIdx.x, t = threadIdx.x;
    int i = c * CHUNK + t;
    int L = labels[i];
    lab[t] = L;
    __syncthreads();
    int rank = 0;
    for (int j = 0; j < t; j++) rank += (lab[j] == L);
    int pos = hist[c * NGRP + L] + rank;
    perm[pos] = i;
    ls[pos] = L;
}

// ---------- segment conv -> tok INTERLEAVED (row 2i = t2_i, row 2i+1 = t4_i) ----------
__global__ __launch_bounds__(256) void k_conv(const float* __restrict__ x,
                                              const int* __restrict__ perm,
                                              const int* __restrict__ ls,
                                              const float* __restrict__ w2, const float* __restrict__ b2,
                                              const float* __restrict__ w4, const float* __restrict__ b4,
                                              unsigned short* __restrict__ tok) {
    const int i = blockIdx.x;
    const int li = ls[i];
    const int p0 = perm[i];
    const int pm1 = (i >= 1 && ls[i - 1] == li) ? perm[i - 1] : -1;
    const int pm2 = (i >= 2 && ls[i - 2] == li) ? perm[i - 2] : -1;
    const int pp1 = (i + 1 < B_N && ls[i + 1] == li) ? perm[i + 1] : -1;
    const int c = threadIdx.x * 4;
    floatx4 z = (floatx4)0.0f;
    floatx4 x0 = *(const floatx4*)(x + (size_t)p0 * D_DIM + c);
    floatx4 xm1 = (pm1 >= 0) ? *(const floatx4*)(x + (size_t)pm1 * D_DIM + c) : z;
    floatx4 xm2 = (pm2 >= 0) ? *(const floatx4*)(x + (size_t)pm2 * D_DIM + c) : z;
    floatx4 xp1 = (pp1 >= 0) ? *(const floatx4*)(x + (size_t)pp1 * D_DIM + c) : z;
    const float w20 = w2[0], w21 = w2[1], cb2 = b2[0];
    const float w40 = w4[0], w41 = w4[1], w42 = w4[2], w43 = w4[3], cb4 = b4[0];
    ushort4v o2, o4;
#pragma unroll
    for (int j = 0; j < 4; j++) {
        float t2 = w20 * xm1[j] + w21 * x0[j] + cb2;
        float t4 = w40 * xm2[j] + w41 * xm1[j] + w42 * x0[j] + w43 * xp1[j] + cb4;
        o2[j] = f2bf(t2);
        o4[j] = f2bf(t4);
    }
    *(ushort4v*)(tok + (size_t)(2 * i) * D_DIM + c) = o2;
    *(ushort4v*)(tok + (size_t)(2 * i + 1) * D_DIM + c) = o4;
}

// ---------- fused weight prep: cast Wqk (2M), linwb (1M); transpose-cast WoT, WvT ----------
__global__ __launch_bounds__(256) void k_prep(const float* __restrict__ intra_in_w,
                                              const float* __restrict__ lin_w,
                                              const float* __restrict__ intra_out_w,
                                              unsigned short* __restrict__ Wqk,
                                              unsigned short* __restrict__ linwb,
                                              unsigned short* __restrict__ WoT,
                                              unsigned short* __restrict__ WvT) {
    __shared__ float tile[32][33];
    const int bx = blockIdx.x;
    if (bx < 3072) {
        int i = bx * 256 + threadIdx.x;
        const float* src;
        unsigned short* dst;
        int j;
        if (i < 524288) { src = intra_in_w; dst = Wqk; j = i; }
        else { src = lin_w; dst = linwb; j = i - 524288; }
        floatx4 v = *(const floatx4*)(src + (size_t)j * 4);
        ushort4v o;
#pragma unroll
        for (int q = 0; q < 4; q++) o[q] = f2bf(v[q]);
        *(ushort4v*)(dst + (size_t)j * 4) = o;
    } else {
        int tb = bx - 3072;
        const float* src;
        unsigned short* dst;
        if (tb < 1024) { src = intra_out_w; dst = WoT; }
        else { src = intra_in_w + (size_t)2048 * D_DIM; dst = WvT; tb -= 1024; }
        const int bX = (tb & 31) * 32, bY = (tb >> 5) * 32;
        const int tx = threadIdx.x & 31, ty = threadIdx.x >> 5;
        for (int r = ty; r < 32; r += 8)
            tile[r][tx] = src[(size_t)(bY + r) * D_DIM + bX + tx];
        __syncthreads();
        for (int r = ty; r < 32; r += 8)
            dst[(size_t)(bX + r) * D_DIM + bY + tx] = f2bf(tile[tx][r]);
    }
}

// ---------- ob2 = intra_out_b + Wo @ bv  (folds v-bias through out-proj) ----------
__global__ __launch_bounds__(256) void k_ob2(const float* __restrict__ ow,
                                             const float* __restrict__ ob,
                                             const float* __restrict__ bv,
                                             float* __restrict__ ob2) {
    int e = blockIdx.x * 256 + threadIdx.x;
    const floatx4* wr4 = (const floatx4*)(ow + (size_t)e * D_DIM);
    const floatx4* bv4 = (const floatx4*)bv;
    float s = ob[e];
    for (int k4 = 0; k4 < D_DIM / 4; k4++) {
        floatx4 a = wr4[k4], b = bv4[k4];
        s += a[0] * b[0] + a[1] * b[1] + a[2] * b[2] + a[3] * b[3];
    }
    ob2[e] = s;
}

// ---------- inter path (fp32, tiny); blockIdx.y==NGRP computes biasc ----------
__global__ __launch_bounds__(256) void k_u(const float* __restrict__ x,
                                           const int* __restrict__ perm,
                                           const int* __restrict__ gstart,
                                           const int* __restrict__ counts,
                                           const float* __restrict__ Wfull,
                                           const float* __restrict__ bfull,
                                           float* __restrict__ u,
                                           const float* __restrict__ lin_w,
                                           const float* __restrict__ lin_b,
                                           const float* __restrict__ ob2,
                                           float* __restrict__ biasc) {
    const int g = blockIdx.y;
    const int n = blockIdx.x * 256 + threadIdx.x;
    __shared__ __align__(16) float xr[D_DIM];
    const bool isb = (g == NGRP);
    int row = 0;
    if (!isb) {
        const int cnt = counts[g];
        row = (cnt > 0) ? perm[gstart[g]] : 0;
    }
    for (int k = threadIdx.x; k < D_DIM; k += 256)
        xr[k] = isb ? ob2[k] : x[(size_t)row * D_DIM + k];
    __syncthreads();
    const float* wrow = isb ? (lin_w + (size_t)n * D_DIM)
                            : (Wfull + (size_t)(2 * D_DIM + n) * D_DIM);
    const floatx4* wr4 = (const floatx4*)wrow;
    const floatx4* xr4 = (const floatx4*)xr;
    float s = isb ? lin_b[n] : bfull[2 * D_DIM + n];
    for (int k4 = 0; k4 < D_DIM / 4; k4++) {
        floatx4 a = xr4[k4], b = wr4[k4];
        s += a[0] * b[0] + a[1] * b[1] + a[2] * b[2] + a[3] * b[3];
    }
    if (isb) biasc[n] = s;
    else u[g * D_DIM + n] = s;
}

__global__ __launch_bounds__(256) void k_f(const float* __restrict__ u,
                                           const int* __restrict__ counts,
                                           const float* __restrict__ W,
                                           const float* __restrict__ b,
                                           float* __restrict__ f) {
    const int g = blockIdx.y;
    const int n = blockIdx.x * 256 + threadIdx.x;
    __shared__ __align__(16) float ur[D_DIM];
    const int cnt = counts[g];
    for (int k = threadIdx.x; k < D_DIM; k += 256) ur[k] = u[g * D_DIM + k];
    __syncthreads();
    const floatx4* wr4 = (const floatx4*)(W + (size_t)n * D_DIM);
    const floatx4* ur4 = (const floatx4*)ur;
    float s = b[n];
    for (int k4 = 0; k4 < D_DIM / 4; k4++) {
        floatx4 a = ur4[k4], w = wr4[k4];
        s += a[0] * w[0] + a[1] * w[1] + a[2] * w[2] + a[3] * w[3];
    }
    f[g * D_DIM + n] = (cnt > 0) ? s : 0.0f;
}

__global__ __launch_bounds__(256) void k_imean(const float* __restrict__ f,
                                               const float* __restrict__ scal,
                                               float* __restrict__ im) {
    int c = blockIdx.x * 256 + threadIdx.x;
    float s = 0.0f;
    for (int g = 0; g < NGRP; g++) s += f[g * D_DIM + c];
    float fl = scal[0];
    for (int g = 0; g < NGRP; g++) im[g * D_DIM + c] = (s - f[g * D_DIM + c]) * fl;
}

// ---------- bf16 MFMA GEMM: C[m][n] = sum_k A[m][k']*W[n][k'] with lda/ldw ----------
// MODE 1: outb[m*ldc + n] = bf16(acc)
// MODE 2: outf[perm[m]][n] = acc + bias[n] + imean[ls[m]][n]   (final, scattered)
template <int MODE>
__global__ __launch_bounds__(256)
void gemm_bt(const unsigned short* __restrict__ A,
             const unsigned short* __restrict__ W,
             int M, int N, int K, int lda, int ldw,
             const float* __restrict__ bias,
             unsigned short* __restrict__ outb, int ldc,
             float* __restrict__ outf,
             const int* __restrict__ perm,
             const int* __restrict__ ls,
             const float* __restrict__ imean) {
    __shared__ __align__(16) unsigned short sA[128 * 64];
    __shared__ __align__(16) unsigned short sB[128 * 64];
    const int t = threadIdx.x;
    const int lane = t & 63, wv = t >> 6;
    int bx = blockIdx.x, by = blockIdx.y;
    const int nX = gridDim.x, nY = gridDim.y;
    if ((nY & 7) == 0) {
        const int bid = by * nX + bx;
        const int xcd = bid & 7, j = bid >> 3;
        const int stripe = nY >> 3;
        by = xcd * stripe + j / nX;
        bx = j % nX;
    }
    const int m0 = by * 128, n0 = bx * 128;
    const int wm = (wv & 1) * 64, wn = (wv >> 1) * 64;
    const int l15 = lane & 15, quad = lane >> 4;
    const int sw = l15 & 7;

    floatx4 acc[4][4];
#pragma unroll
    for (int i = 0; i < 4; i++)
#pragma unroll
        for (int j = 0; j < 4; j++) acc[i][j] = (floatx4)0.0f;

    for (int k0 = 0; k0 < K; k0 += 64) {
#pragma unroll
        for (int r = 0; r < 4; r++) {
            const int chunk = r * 256 + wv * 64;
            const int idx = chunk + lane;
            const int row = idx >> 3;
            const int kb = (idx & 7) ^ (row & 7);
            gload_lds16(A + (size_t)(m0 + row) * lda + k0 + kb * 8, &sA[chunk * 8]);
            gload_lds16(W + (size_t)(n0 + row) * ldw + k0 + kb * 8, &sB[chunk * 8]);
        }
        __syncthreads();
#pragma unroll
        for (int kk = 0; kk < 64; kk += 32) {
            const int kc = kk >> 3;
            short8 av[4], bv[4];
#pragma unroll
            for (int mt = 0; mt < 4; mt++)
                av[mt] = *(const short8*)&sA[(wm + mt * 16 + l15) * 64 +
                                             (((kc + quad) ^ sw) << 3)];
#pragma unroll
            for (int nt = 0; nt < 4; nt++)
                bv[nt] = *(const short8*)&sB[(wn + nt * 16 + l15) * 64 +
                                             (((kc + quad) ^ sw) << 3)];
#pragma unroll
            for (int mt = 0; mt < 4; mt++)
#pragma unroll
                for (int nt = 0; nt < 4; nt++)
                    acc[mt][nt] = __builtin_amdgcn_mfma_f32_16x16x32_bf16(
                        av[mt], bv[nt], acc[mt][nt], 0, 0, 0);
        }
        __syncthreads();
    }

    if (MODE == 1) {
#pragma unroll
        for (int nt = 0; nt < 4; nt++) {
            const int gc = n0 + wn + nt * 16 + l15;
#pragma unroll
            for (int mt = 0; mt < 4; mt++) {
                const int gr = m0 + wm + mt * 16 + quad * 4;
#pragma unroll
                for (int r = 0; r < 4; r++)
                    outb[(size_t)(gr + r) * ldc + gc] = f2bf(acc[mt][nt][r]);
            }
        }
    } else {
        float bb[4];
        int gc4[4];
#pragma unroll
        for (int nt = 0; nt < 4; nt++) {
            gc4[nt] = n0 + wn + nt * 16 + l15;
            bb[nt] = bias[gc4[nt]];
        }
#pragma unroll
        for (int mt = 0; mt < 4; mt++) {
#pragma unroll
            for (int r = 0; r < 4; r++) {
                const int i = m0 + wm + mt * 16 + quad * 4 + r;
                const int orow = perm[i];
                const int lg = ls[i];
#pragma unroll
                for (int nt = 0; nt < 4; nt++)
                    outf[(size_t)orow * N + gc4[nt]] =
                        acc[mt][nt][r] + bb[nt] + imean[lg * D_DIM + gc4[nt]];
            }
        }
    }
}

// ---------- fused q/k projection + score partials (never materializes q,k) ----------
// A = interleaved tok [2*B_N][1024]; block = 128 rows x 64 q/k-cols; dual B (Wq, Wk).
// Epilogue: per pair (rows 2i,2i+1) partial dots over this block's 64 cols, 16-lane
// reduced, stored (no atomics!) to sp[bx*B_N + i] as float4 (s22,s24,s42,s44).
// Each (bx, i) slot is written by exactly one block -> no init, no contention.
__global__ __launch_bounds__(256) void k_qkscore(const unsigned short* __restrict__ A,
                                                 const unsigned short* __restrict__ Wq,
                                                 const unsigned short* __restrict__ Wk,
                                                 const float* __restrict__ bq,
                                                 const float* __restrict__ bk,
                                                 floatx4* __restrict__ sp) {
    __shared__ __align__(16) unsigned short sA[128 * 64];
    __shared__ __align__(16) unsigned short sBq[64 * 64];
    __shared__ __align__(16) unsigned short sBk[64 * 64];
    const int t = threadIdx.x;
    const int lane = t & 63, wv = t >> 6;
    int bx = blockIdx.x, by = blockIdx.y;  // (16, 256)
    {
        const int nX = gridDim.x, nY = gridDim.y;
        const int bid = by * nX + bx;
        const int xcd = bid & 7, j = bid >> 3;
        const int stripe = nY >> 3;
        by = xcd * stripe + j / nX;
        bx = j % nX;
    }
    const int m0 = by * 128, n0 = bx * 64;
    const int wm = (wv & 1) * 64, wn = (wv >> 1) * 32;
    const int l15 = lane & 15, quad = lane >> 4;
    const int sw = l15 & 7;

    floatx4 qa[4][2], ka[4][2];
#pragma unroll
    for (int i = 0; i < 4; i++)
#pragma unroll
        for (int j = 0; j < 2; j++) { qa[i][j] = (floatx4)0.0f; ka[i][j] = (floatx4)0.0f; }

    for (int k0 = 0; k0 < D_DIM; k0 += 64) {
#pragma unroll
        for (int r = 0; r < 4; r++) {
            const int chunk = r * 256 + wv * 64;
            const int idx = chunk + lane;
            const int row = idx >> 3;
            const int kb = (idx & 7) ^ (row & 7);
            gload_lds16(A + (size_t)(m0 + row) * D_DIM + k0 + kb * 8, &sA[chunk * 8]);
        }
#pragma unroll
        for (int r = 0; r < 2; r++) {
            const int chunk = r * 256 + wv * 64;
            const int idx = chunk + lane;
            const int row = idx >> 3;  // 0..63
            const int kb = (idx & 7) ^ (row & 7);
            gload_lds16(Wq + (size_t)(n0 + row) * D_DIM + k0 + kb * 8, &sBq[chunk * 8]);
            gload_lds16(Wk + (size_t)(n0 + row) * D_DIM + k0 + kb * 8, &sBk[chunk * 8]);
        }
        __syncthreads();
#pragma unroll
        for (int kk = 0; kk < 64; kk += 32) {
            const int kc = kk >> 3;
            short8 av[4], bqv[2], bkv[2];
#pragma unroll
            for (int mt = 0; mt < 4; mt++)
                av[mt] = *(const short8*)&sA[(wm + mt * 16 + l15) * 64 +
                                             (((kc + quad) ^ sw) << 3)];
#pragma unroll
            for (int nt = 0; nt < 2; nt++) {
                bqv[nt] = *(const short8*)&sBq[(wn + nt * 16 + l15) * 64 +
                                               (((kc + quad) ^ sw) << 3)];
                bkv[nt] = *(const short8*)&sBk[(wn + nt * 16 + l15) * 64 +
                                               (((kc + quad) ^ sw) << 3)];
            }
#pragma unroll
            for (int mt = 0; mt < 4; mt++)
#pragma unroll
                for (int nt = 0; nt < 2; nt++) {
                    qa[mt][nt] = __builtin_amdgcn_mfma_f32_16x16x32_bf16(
                        av[mt], bqv[nt], qa[mt][nt], 0, 0, 0);
                    ka[mt][nt] = __builtin_amdgcn_mfma_f32_16x16x32_bf16(
                        av[mt], bkv[nt], ka[mt][nt], 0, 0, 0);
                }
        }
        __syncthreads();
    }

    float bqv2[2], bkv2[2];
#pragma unroll
    for (int nt = 0; nt < 2; nt++) {
        const int col = n0 + wn + nt * 16 + l15;
        bqv2[nt] = bq[col];
        bkv2[nt] = bk[col];
    }
#pragma unroll
    for (int mt = 0; mt < 4; mt++) {
#pragma unroll
        for (int p = 0; p < 2; p++) {
            float s22 = 0, s24 = 0, s42 = 0, s44 = 0;
#pragma unroll
            for (int nt = 0; nt < 2; nt++) {
                float q0 = qa[mt][nt][2 * p] + bqv2[nt];
                float q1 = qa[mt][nt][2 * p + 1] + bqv2[nt];
                float k0v = ka[mt][nt][2 * p] + bkv2[nt];
                float k1v = ka[mt][nt][2 * p + 1] + bkv2[nt];
                s22 += q0 * k0v; s24 += q0 * k1v; s42 += q1 * k0v; s44 += q1 * k1v;
            }
#pragma unroll
            for (int d = 1; d < 16; d <<= 1) {
                s22 += __shfl_xor(s22, d, 64);
                s24 += __shfl_xor(s24, d, 64);
                s42 += __shfl_xor(s42, d, 64);
                s44 += __shfl_xor(s44, d, 64);
            }
            if (l15 == 0) {
                const int i = (m0 + wm + mt * 16 + quad * 4 + 2 * p) >> 1;
                floatx4 v;
                v[0] = s22; v[1] = s24; v[2] = s42; v[3] = s44;
                sp[(size_t)bx * B_N + i] = v;
            }
        }
    }
}

// ---------- partial-sum reduce + softmax -> gamma ----------
__global__ __launch_bounds__(256) void k_gam(const floatx4* __restrict__ sp,
                                             floatx4* __restrict__ gam) {
    const int i = blockIdx.x * 256 + threadIdx.x;
    float a[8];
#pragma unroll
    for (int j = 0; j < 8; j++) a[j] = 0.0f;
#pragma unroll
    for (int b = 0; b < 16; b++) {
        floatx4 v = sp[(size_t)b * B_N + i];
        const int h4 = (b >> 3) * 4;
        a[h4 + 0] += v[0]; a[h4 + 1] += v[1]; a[h4 + 2] += v[2]; a[h4 + 3] += v[3];
    }
    const float sc = 0.044194173824159216f;  // 1/sqrt(512)
    floatx4 g;
#pragma unroll
    for (int h = 0; h < 2; h++) {
        float s22 = a[h * 4 + 0] * sc, s24 = a[h * 4 + 1] * sc;
        float s42 = a[h * 4 + 2] * sc, s44 = a[h * 4 + 3] * sc;
        float m0 = fmaxf(s22, s24), e22 = __expf(s22 - m0), e24 = __expf(s24 - m0);
        float w24 = e24 / (e22 + e24), w22 = 1.0f - w24;
        float m1 = fmaxf(s42, s44), e42 = __expf(s42 - m1), e44 = __expf(s44 - m1);
        float w44 = e44 / (e42 + e44), w42 = 1.0f - w44;
        g[h * 2 + 0] = 0.5f * (w22 + w42);
        g[h * 2 + 1] = 0.5f * (w24 + w44);
    }
    gam[i] = g;
}

// ---------- in-place gamma-combine: rows (2i,2i+1) of tok become [z1|z2] ----------
__global__ __launch_bounds__(256) void k_zprep(unsigned short* __restrict__ tok,
                                               const floatx4* __restrict__ gam) {
    const int idx = blockIdx.x * 256 + threadIdx.x;  // B_N*128 threads
    const int i = idx >> 7;
    const int seg = (idx & 127) * 8;
    floatx4 g = gam[i];
    short8 a = *(const short8*)(tok + (size_t)(2 * i) * D_DIM + seg);
    short8 b = *(const short8*)(tok + (size_t)(2 * i + 1) * D_DIM + seg);
    ushort8 z1, z2;
#pragma unroll
    for (int j = 0; j < 8; j++) {
        float af = bf2f((unsigned short)a[j]), bf = bf2f((unsigned short)b[j]);
        z1[j] = f2bf(g[0] * af + g[1] * bf);
        z2[j] = f2bf(g[2] * af + g[3] * bf);
    }
    *(ushort8*)(tok + (size_t)(2 * i) * D_DIM + seg) = z1;
    *(ushort8*)(tok + (size_t)(2 * i + 1) * D_DIM + seg) = z2;
}

extern "C" void kernel_launch(void* const* d_in, const int* in_sizes, int n_in,
                              void* d_out, int out_size, void* d_ws, size_t ws_size,
                              hipStream_t stream) {
    const float* x = (const float*)d_in[0];
    const int* labels = (const int*)d_in[1];
    const float* conv_w2 = (const float*)d_in[3];
    const float* conv_b2 = (const float*)d_in[4];
    const float* conv_w4 = (const float*)d_in[5];
    const float* conv_b4 = (const float*)d_in[6];
    const float* intra_in_w = (const float*)d_in[7];
    const float* intra_in_b = (const float*)d_in[8];
    const float* intra_out_w = (const float*)d_in[9];
    const float* intra_out_b = (const float*)d_in[10];
    const float* inter_in_w = (const float*)d_in[11];
    const float* inter_in_b = (const float*)d_in[12];
    const float* inter_out_w = (const float*)d_in[13];
    const float* inter_out_b = (const float*)d_in[14];
    const float* lin_w = (const float*)d_in[15];
    const float* lin_b = (const float*)d_in[16];
    float* out = (float*)d_out;

    char* p = (char*)d_ws;
    auto alloc = [&](size_t bytes) -> void* {
        void* r = (void*)p;
        p += (bytes + 255) & ~(size_t)255;
        return r;
    };
    int* perm = (int*)alloc(B_N * 4);
    int* lss = (int*)alloc(B_N * 4);
    int* hist = (int*)alloc(NCHUNK * NGRP * 4);
    int* gstart = (int*)alloc((NGRP + 1) * 4);
    int* counts = (int*)alloc(NGRP * 4);
    float* scal = (float*)alloc(4);
    unsigned short* tok = (unsigned short*)alloc((size_t)2 * B_N * D_DIM * 2);   // 64 MB
    unsigned short* Wqk = (unsigned short*)alloc((size_t)2 * D_DIM * D_DIM * 2); // 4 MB
    unsigned short* linwb = (unsigned short*)alloc((size_t)D_DIM * D_DIM * 2);
    unsigned short* WoT = (unsigned short*)alloc((size_t)D_DIM * D_DIM * 2);
    unsigned short* WvT = (unsigned short*)alloc((size_t)D_DIM * D_DIM * 2);
    unsigned short* Wc = (unsigned short*)alloc((size_t)D_DIM * D_DIM * 2);
    unsigned short* GG = (unsigned short*)alloc((size_t)D_DIM * 2 * D_DIM * 2);  // 4 MB
    floatx4* sp = (floatx4*)alloc((size_t)16 * B_N * 16);                        // 4 MB
    floatx4* gam = (floatx4*)alloc((size_t)B_N * 16);
    float* u = (float*)alloc((size_t)NGRP * D_DIM * 4);
    float* fbuf = (float*)alloc((size_t)NGRP * D_DIM * 4);
    float* imean = (float*)alloc((size_t)NGRP * D_DIM * 4);
    float* biasc = (float*)alloc(D_DIM * 4);
    float* ob2 = (float*)alloc(D_DIM * 4);

    // ---- sort ----
    k_hist<<<NCHUNK, CHUNK, 0, stream>>>(labels, hist);
    k_scan<<<1, NGRP, 0, stream>>>(hist, gstart, counts, scal);
    k_scatter<<<NCHUNK, CHUNK, 0, stream>>>(labels, hist, perm, lss);
    // ---- weight prep ----
    k_prep<<<3072 + 2048, 256, 0, stream>>>(intra_in_w, lin_w, intra_out_w, Wqk, linwb,
                                            WoT, WvT);
    gemm_bt<1><<<dim3(8, 8), 256, 0, stream>>>(linwb, WoT, 1024, 1024, 1024, 1024, 1024,
                                               nullptr, Wc, 1024, nullptr, nullptr,
                                               nullptr, nullptr);
    // GG[n][h*1024+k] = sum_e Wc[n][h*512+e] * WvT[k][h*512+e]
    gemm_bt<1><<<dim3(8, 8), 256, 0, stream>>>(Wc, WvT, 1024, 1024, 512, 1024, 1024,
                                               nullptr, GG, 2048, nullptr, nullptr,
                                               nullptr, nullptr);
    gemm_bt<1><<<dim3(8, 8), 256, 0, stream>>>(Wc + 512, WvT + 512, 1024, 1024, 512, 1024,
                                               1024, nullptr, GG + 1024, 2048, nullptr,
                                               nullptr, nullptr, nullptr);
    k_ob2<<<4, 256, 0, stream>>>(intra_out_w, intra_out_b, intra_in_b + 2 * D_DIM, ob2);
    // ---- inter path (fp32) + biasc ----
    k_u<<<dim3(4, NGRP + 1), 256, 0, stream>>>(x, perm, gstart, counts, inter_in_w,
                                               inter_in_b, u, lin_w, lin_b, ob2, biasc);
    k_f<<<dim3(4, NGRP), 256, 0, stream>>>(u, counts, inter_out_w, inter_out_b, fbuf);
    k_imean<<<4, 256, 0, stream>>>(fbuf, scal, imean);
    // ---- conv -> interleaved tok ----
    k_conv<<<B_N, 256, 0, stream>>>(x, perm, lss, conv_w2, conv_b2, conv_w4, conv_b4, tok);
    // ---- fused qk + score partials (no atomics) ----
    k_qkscore<<<dim3(16, 256), 256, 0, stream>>>(tok, Wqk, Wqk + (size_t)D_DIM * D_DIM,
                                                 intra_in_b, intra_in_b + D_DIM, sp);
    k_gam<<<B_N / 256, 256, 0, stream>>>(sp, gam);
    k_zprep<<<B_N / 2, 256, 0, stream>>>(tok, gam);
    // ---- merged v+out GEMM: out[perm[i]] = [z1|z2] . GG^T + biasc + imean ----
    gemm_bt<2><<<dim3(8, 128), 256, 0, stream>>>(tok, GG, B_N, 1024, 2048, 2048, 2048,
                                                 biasc, nullptr, 0, out, perm, lss, imean);
}

// Round 7
// 599.569 us; speedup vs baseline: 1.5888x; 1.0426x over previous
//
#include <hip/hip_runtime.h>
#include <hip/hip_bf16.h>

#define B_N 16384
#define D_DIM 1024
#define NGRP 64
#define NCHUNK 64
#define CHUNK 256

typedef __attribute__((ext_vector_type(8))) short short8;
typedef __attribute__((ext_vector_type(8))) unsigned short ushort8;
typedef __attribute__((ext_vector_type(4))) unsigned short ushort4v;
typedef __attribute__((ext_vector_type(4))) float floatx4;

__device__ __forceinline__ float bf2f(unsigned short h) {
    union { unsigned u; float f; } c; c.u = ((unsigned)h) << 16; return c.f;
}
__device__ __forceinline__ unsigned short f2bf(float f) {
    union { float f; unsigned u; } c; c.f = f;
    unsigned r = c.u + 0x7FFFu + ((c.u >> 16) & 1u);
    return (unsigned short)(r >> 16);
}

__device__ __forceinline__ void gload_lds16(const void* g, void* l) {
    __builtin_amdgcn_global_load_lds(
        (const __attribute__((address_space(1))) unsigned int*)g,
        (__attribute__((address_space(3))) unsigned int*)l, 16, 0, 0);
}

// ---------- stable counting sort ----------
__global__ __launch_bounds__(256) void k_hist(const int* __restrict__ labels,
                                              int* __restrict__ hist) {
    __shared__ int lh[NGRP];
    int t = threadIdx.x, c = blockIdx.x;
    if (t < NGRP) lh[t] = 0;
    __syncthreads();
    int lab = labels[c * CHUNK + t];
    atomicAdd(&lh[lab], 1);
    __syncthreads();
    if (t < NGRP) hist[c * NGRP + t] = lh[t];
}

__global__ void k_scan(int* __restrict__ hist, int* __restrict__ gstart,
                       int* __restrict__ counts, float* __restrict__ scal) {
    __shared__ int cnt[NGRP];
    __shared__ int st[NGRP + 1];
    int g = threadIdx.x;
    int run = 0;
    for (int c = 0; c < NCHUNK; c++) {
        int v = hist[c * NGRP + g];
        hist[c * NGRP + g] = run;
        run += v;
    }
    cnt[g] = run;
    counts[g] = run;
    __syncthreads();
    if (g == 0) {
        int s = 0, np = 0;
        for (int i = 0; i < NGRP; i++) { st[i] = s; s += cnt[i]; np += (cnt[i] > 0); }
        st[NGRP] = s;
        scal[0] = (np > 1) ? 1.0f / (float)(np - 1) : 0.0f;
    }
    __syncthreads();
    gstart[g] = st[g];
    if (g == 0) gstart[NGRP] = st[NGRP];
    for (int c = 0; c < NCHUNK; c++) hist[c * NGRP + g] += st[g];
}

__global__ __launch_bounds__(256) void k_scatter(const int* __restrict__ labels,
                                                 const int* __restrict__ hist,
                                                 int* __restrict__ perm,
                                                 int* __restrict__ ls) {
    __shared__ int lab[CHUNK];
    int c = blockIdx.x, t = threadIdx.x;
    int i = c * CHUNK + t;
    int L = labels[i];
    lab[t] = L;
    __syncthreads();
    int rank = 0;
    for (int j = 0; j < t; j++) rank += (lab[j] == L);
    int pos = hist[c * NGRP + L] + rank;
    perm[pos] = i;
    ls[pos] = L;
}

// ---------- segment conv, 4 rows/block (neighbor loads shared) ----------
// tok INTERLEAVED: row 2i = t2_i, row 2i+1 = t4_i
__global__ __launch_bounds__(256) void k_conv(const float* __restrict__ x,
                                              const int* __restrict__ perm,
                                              const int* __restrict__ ls,
                                              const float* __restrict__ w2, const float* __restrict__ b2,
                                              const float* __restrict__ w4, const float* __restrict__ b4,
                                              unsigned short* __restrict__ tok) {
    const int i0 = blockIdx.x * 4;
    const int c = threadIdx.x * 4;
    int lab[7];
    floatx4 xr[7];
    const floatx4 z = (floatx4)0.0f;
#pragma unroll
    for (int j = 0; j < 7; j++) {
        const int idx = i0 + j - 2;
        const bool v = (idx >= 0 && idx < B_N);
        lab[j] = v ? ls[idx] : -1;
        const int pr = v ? perm[idx] : 0;
        xr[j] = v ? *(const floatx4*)(x + (size_t)pr * D_DIM + c) : z;
    }
    const float w20 = w2[0], w21 = w2[1], cb2 = b2[0];
    const float w40 = w4[0], w41 = w4[1], w42 = w4[2], w43 = w4[3], cb4 = b4[0];
#pragma unroll
    for (int k = 0; k < 4; k++) {
        const int li = lab[k + 2];
        floatx4 m2 = (lab[k] == li) ? xr[k] : z;
        floatx4 m1 = (lab[k + 1] == li) ? xr[k + 1] : z;
        floatx4 x0 = xr[k + 2];
        floatx4 p1 = (lab[k + 3] == li) ? xr[k + 3] : z;
        ushort4v o2, o4;
#pragma unroll
        for (int j = 0; j < 4; j++) {
            float t2 = w20 * m1[j] + w21 * x0[j] + cb2;
            float t4 = w40 * m2[j] + w41 * m1[j] + w42 * x0[j] + w43 * p1[j] + cb4;
            o2[j] = f2bf(t2);
            o4[j] = f2bf(t4);
        }
        const int i = i0 + k;
        *(ushort4v*)(tok + (size_t)(2 * i) * D_DIM + c) = o2;
        *(ushort4v*)(tok + (size_t)(2 * i + 1) * D_DIM + c) = o4;
    }
}

// ---------- fused weight prep: cast Wqk/linwb, transpose-cast WoT/WvT, + ob2 ----------
__global__ __launch_bounds__(256) void k_prep(const float* __restrict__ intra_in_w,
                                              const float* __restrict__ lin_w,
                                              const float* __restrict__ intra_out_w,
                                              const float* __restrict__ intra_out_b,
                                              unsigned short* __restrict__ Wqk,
                                              unsigned short* __restrict__ linwb,
                                              unsigned short* __restrict__ WoT,
                                              unsigned short* __restrict__ WvT,
                                              const float* __restrict__ bv,
                                              float* __restrict__ ob2) {
    __shared__ float tile[32][33];
    const int bx = blockIdx.x;
    if (bx < 3072) {
        int i = bx * 256 + threadIdx.x;
        const float* src;
        unsigned short* dst;
        int j;
        if (i < 524288) { src = intra_in_w; dst = Wqk; j = i; }
        else { src = lin_w; dst = linwb; j = i - 524288; }
        floatx4 v = *(const floatx4*)(src + (size_t)j * 4);
        ushort4v o;
#pragma unroll
        for (int q = 0; q < 4; q++) o[q] = f2bf(v[q]);
        *(ushort4v*)(dst + (size_t)j * 4) = o;
    } else if (bx < 5120) {
        int tb = bx - 3072;
        const float* src;
        unsigned short* dst;
        if (tb < 1024) { src = intra_out_w; dst = WoT; }
        else { src = intra_in_w + (size_t)2048 * D_DIM; dst = WvT; tb -= 1024; }
        const int bX = (tb & 31) * 32, bY = (tb >> 5) * 32;
        const int tx = threadIdx.x & 31, ty = threadIdx.x >> 5;
        for (int r = ty; r < 32; r += 8)
            tile[r][tx] = src[(size_t)(bY + r) * D_DIM + bX + tx];
        __syncthreads();
        for (int r = ty; r < 32; r += 8)
            dst[(size_t)(bX + r) * D_DIM + bY + tx] = f2bf(tile[tx][r]);
    } else {
        // ob2 = intra_out_b + Wo @ bv
        const int e = (bx - 5120) * 256 + threadIdx.x;
        const floatx4* wr4 = (const floatx4*)(intra_out_w + (size_t)e * D_DIM);
        const floatx4* bv4 = (const floatx4*)bv;
        float s = intra_out_b[e];
        for (int k4 = 0; k4 < D_DIM / 4; k4++) {
            floatx4 a = wr4[k4], b = bv4[k4];
            s += a[0] * b[0] + a[1] * b[1] + a[2] * b[2] + a[3] * b[3];
        }
        ob2[e] = s;
    }
}

// ---------- inter path (fp32, tiny); blockIdx.y==NGRP computes biasc ----------
__global__ __launch_bounds__(256) void k_u(const float* __restrict__ x,
                                           const int* __restrict__ perm,
                                           const int* __restrict__ gstart,
                                           const int* __restrict__ counts,
                                           const float* __restrict__ Wfull,
                                           const float* __restrict__ bfull,
                                           float* __restrict__ u,
                                           const float* __restrict__ lin_w,
                                           const float* __restrict__ lin_b,
                                           const float* __restrict__ ob2,
                                           float* __restrict__ biasc) {
    const int g = blockIdx.y;
    const int n = blockIdx.x * 256 + threadIdx.x;
    __shared__ __align__(16) float xr[D_DIM];
    const bool isb = (g == NGRP);
    int row = 0;
    if (!isb) {
        const int cnt = counts[g];
        row = (cnt > 0) ? perm[gstart[g]] : 0;
    }
    for (int k = threadIdx.x; k < D_DIM; k += 256)
        xr[k] = isb ? ob2[k] : x[(size_t)row * D_DIM + k];
    __syncthreads();
    const float* wrow = isb ? (lin_w + (size_t)n * D_DIM)
                            : (Wfull + (size_t)(2 * D_DIM + n) * D_DIM);
    const floatx4* wr4 = (const floatx4*)wrow;
    const floatx4* xr4 = (const floatx4*)xr;
    float s = isb ? lin_b[n] : bfull[2 * D_DIM + n];
    for (int k4 = 0; k4 < D_DIM / 4; k4++) {
        floatx4 a = xr4[k4], b = wr4[k4];
        s += a[0] * b[0] + a[1] * b[1] + a[2] * b[2] + a[3] * b[3];
    }
    if (isb) biasc[n] = s;
    else u[g * D_DIM + n] = s;
}

__global__ __launch_bounds__(256) void k_f(const float* __restrict__ u,
                                           const int* __restrict__ counts,
                                           const float* __restrict__ W,
                                           const float* __restrict__ b,
                                           float* __restrict__ f) {
    const int g = blockIdx.y;
    const int n = blockIdx.x * 256 + threadIdx.x;
    __shared__ __align__(16) float ur[D_DIM];
    const int cnt = counts[g];
    for (int k = threadIdx.x; k < D_DIM; k += 256) ur[k] = u[g * D_DIM + k];
    __syncthreads();
    const floatx4* wr4 = (const floatx4*)(W + (size_t)n * D_DIM);
    const floatx4* ur4 = (const floatx4*)ur;
    float s = b[n];
    for (int k4 = 0; k4 < D_DIM / 4; k4++) {
        floatx4 a = ur4[k4], w = wr4[k4];
        s += a[0] * w[0] + a[1] * w[1] + a[2] * w[2] + a[3] * w[3];
    }
    f[g * D_DIM + n] = (cnt > 0) ? s : 0.0f;
}

__global__ __launch_bounds__(256) void k_imean(const float* __restrict__ f,
                                               const float* __restrict__ scal,
                                               float* __restrict__ im) {
    int c = blockIdx.x * 256 + threadIdx.x;
    float s = 0.0f;
    for (int g = 0; g < NGRP; g++) s += f[g * D_DIM + c];
    float fl = scal[0];
    for (int g = 0; g < NGRP; g++) im[g * D_DIM + c] = (s - f[g * D_DIM + c]) * fl;
}

// ---------- bf16 MFMA GEMM: C[m][n] = sum_k A[m][k']*W[n][k'] with lda/ldw ----------
// MODE 1: outb[m*ldc + n] = bf16(acc)
// MODE 2: outf[perm[m]][n] = acc + bias[n] + imean[ls[m]][n]   (final, scattered)
// MODE 3: dual-GG: n0>=1024 selects head 1 (A,W k-offset +512, W row n0-1024)
template <int MODE>
__global__ __launch_bounds__(256)
void gemm_bt(const unsigned short* __restrict__ A,
             const unsigned short* __restrict__ W,
             int M, int N, int K, int lda, int ldw,
             const float* __restrict__ bias,
             unsigned short* __restrict__ outb, int ldc,
             float* __restrict__ outf,
             const int* __restrict__ perm,
             const int* __restrict__ ls,
             const float* __restrict__ imean) {
    __shared__ __align__(16) unsigned short sA[128 * 64];
    __shared__ __align__(16) unsigned short sB[128 * 64];
    const int t = threadIdx.x;
    const int lane = t & 63, wv = t >> 6;
    int bx = blockIdx.x, by = blockIdx.y;
    const int nX = gridDim.x, nY = gridDim.y;
    if ((nY & 7) == 0) {
        const int bid = by * nX + bx;
        const int xcd = bid & 7, j = bid >> 3;
        const int stripe = nY >> 3;
        by = xcd * stripe + j / nX;
        bx = j % nX;
    }
    const int m0 = by * 128, n0 = bx * 128;
    const unsigned short* Ap = A;
    const unsigned short* Wp = W + (size_t)n0 * ldw;
    if (MODE == 3 && n0 >= 1024) {
        Ap = A + 512;
        Wp = W + (size_t)(n0 - 1024) * ldw + 512;
    }
    const int wm = (wv & 1) * 64, wn = (wv >> 1) * 64;
    const int l15 = lane & 15, quad = lane >> 4;
    const int sw = l15 & 7;

    floatx4 acc[4][4];
#pragma unroll
    for (int i = 0; i < 4; i++)
#pragma unroll
        for (int j = 0; j < 4; j++) acc[i][j] = (floatx4)0.0f;

    for (int k0 = 0; k0 < K; k0 += 64) {
#pragma unroll
        for (int r = 0; r < 4; r++) {
            const int chunk = r * 256 + wv * 64;
            const int idx = chunk + lane;
            const int row = idx >> 3;
            const int kb = (idx & 7) ^ (row & 7);
            gload_lds16(Ap + (size_t)(m0 + row) * lda + k0 + kb * 8, &sA[chunk * 8]);
            gload_lds16(Wp + (size_t)row * ldw + k0 + kb * 8, &sB[chunk * 8]);
        }
        __syncthreads();
#pragma unroll
        for (int kk = 0; kk < 64; kk += 32) {
            const int kc = kk >> 3;
            short8 av[4], bv[4];
#pragma unroll
            for (int mt = 0; mt < 4; mt++)
                av[mt] = *(const short8*)&sA[(wm + mt * 16 + l15) * 64 +
                                             (((kc + quad) ^ sw) << 3)];
#pragma unroll
            for (int nt = 0; nt < 4; nt++)
                bv[nt] = *(const short8*)&sB[(wn + nt * 16 + l15) * 64 +
                                             (((kc + quad) ^ sw) << 3)];
#pragma unroll
            for (int mt = 0; mt < 4; mt++)
#pragma unroll
                for (int nt = 0; nt < 4; nt++)
                    acc[mt][nt] = __builtin_amdgcn_mfma_f32_16x16x32_bf16(
                        av[mt], bv[nt], acc[mt][nt], 0, 0, 0);
        }
        __syncthreads();
    }

    if (MODE != 2) {
#pragma unroll
        for (int nt = 0; nt < 4; nt++) {
            const int gc = n0 + wn + nt * 16 + l15;
#pragma unroll
            for (int mt = 0; mt < 4; mt++) {
                const int gr = m0 + wm + mt * 16 + quad * 4;
#pragma unroll
                for (int r = 0; r < 4; r++)
                    outb[(size_t)(gr + r) * ldc + gc] = f2bf(acc[mt][nt][r]);
            }
        }
    } else {
        float bb[4];
        int gc4[4];
#pragma unroll
        for (int nt = 0; nt < 4; nt++) {
            gc4[nt] = n0 + wn + nt * 16 + l15;
            bb[nt] = bias[gc4[nt]];
        }
#pragma unroll
        for (int mt = 0; mt < 4; mt++) {
#pragma unroll
            for (int r = 0; r < 4; r++) {
                const int i = m0 + wm + mt * 16 + quad * 4 + r;
                const int orow = perm[i];
                const int lg = ls[i];
#pragma unroll
                for (int nt = 0; nt < 4; nt++)
                    outf[(size_t)orow * N + gc4[nt]] =
                        acc[mt][nt][r] + bb[nt] + imean[lg * D_DIM + gc4[nt]];
            }
        }
    }
}

// ---------- fused q/k projection + score partials (no atomics) ----------
__global__ __launch_bounds__(256) void k_qkscore(const unsigned short* __restrict__ A,
                                                 const unsigned short* __restrict__ Wq,
                                                 const unsigned short* __restrict__ Wk,
                                                 const float* __restrict__ bq,
                                                 const float* __restrict__ bk,
                                                 floatx4* __restrict__ sp) {
    __shared__ __align__(16) unsigned short sA[128 * 64];
    __shared__ __align__(16) unsigned short sBq[64 * 64];
    __shared__ __align__(16) unsigned short sBk[64 * 64];
    const int t = threadIdx.x;
    const int lane = t & 63, wv = t >> 6;
    int bx = blockIdx.x, by = blockIdx.y;  // (16, 256)
    {
        const int nX = gridDim.x, nY = gridDim.y;
        const int bid = by * nX + bx;
        const int xcd = bid & 7, j = bid >> 3;
        const int stripe = nY >> 3;
        by = xcd * stripe + j / nX;
        bx = j % nX;
    }
    const int m0 = by * 128, n0 = bx * 64;
    const int wm = (wv & 1) * 64, wn = (wv >> 1) * 32;
    const int l15 = lane & 15, quad = lane >> 4;
    const int sw = l15 & 7;

    floatx4 qa[4][2], ka[4][2];
#pragma unroll
    for (int i = 0; i < 4; i++)
#pragma unroll
        for (int j = 0; j < 2; j++) { qa[i][j] = (floatx4)0.0f; ka[i][j] = (floatx4)0.0f; }

    for (int k0 = 0; k0 < D_DIM; k0 += 64) {
#pragma unroll
        for (int r = 0; r < 4; r++) {
            const int chunk = r * 256 + wv * 64;
            const int idx = chunk + lane;
            const int row = idx >> 3;
            const int kb = (idx & 7) ^ (row & 7);
            gload_lds16(A + (size_t)(m0 + row) * D_DIM + k0 + kb * 8, &sA[chunk * 8]);
        }
#pragma unroll
        for (int r = 0; r < 2; r++) {
            const int chunk = r * 256 + wv * 64;
            const int idx = chunk + lane;
            const int row = idx >> 3;  // 0..63
            const int kb = (idx & 7) ^ (row & 7);
            gload_lds16(Wq + (size_t)(n0 + row) * D_DIM + k0 + kb * 8, &sBq[chunk * 8]);
            gload_lds16(Wk + (size_t)(n0 + row) * D_DIM + k0 + kb * 8, &sBk[chunk * 8]);
        }
        __syncthreads();
#pragma unroll
        for (int kk = 0; kk < 64; kk += 32) {
            const int kc = kk >> 3;
            short8 av[4], bqv[2], bkv[2];
#pragma unroll
            for (int mt = 0; mt < 4; mt++)
                av[mt] = *(const short8*)&sA[(wm + mt * 16 + l15) * 64 +
                                             (((kc + quad) ^ sw) << 3)];
#pragma unroll
            for (int nt = 0; nt < 2; nt++) {
                bqv[nt] = *(const short8*)&sBq[(wn + nt * 16 + l15) * 64 +
                                               (((kc + quad) ^ sw) << 3)];
                bkv[nt] = *(const short8*)&sBk[(wn + nt * 16 + l15) * 64 +
                                               (((kc + quad) ^ sw) << 3)];
            }
#pragma unroll
            for (int mt = 0; mt < 4; mt++)
#pragma unroll
                for (int nt = 0; nt < 2; nt++) {
                    qa[mt][nt] = __builtin_amdgcn_mfma_f32_16x16x32_bf16(
                        av[mt], bqv[nt], qa[mt][nt], 0, 0, 0);
                    ka[mt][nt] = __builtin_amdgcn_mfma_f32_16x16x32_bf16(
                        av[mt], bkv[nt], ka[mt][nt], 0, 0, 0);
                }
        }
        __syncthreads();
    }

    float bqv2[2], bkv2[2];
#pragma unroll
    for (int nt = 0; nt < 2; nt++) {
        const int col = n0 + wn + nt * 16 + l15;
        bqv2[nt] = bq[col];
        bkv2[nt] = bk[col];
    }
#pragma unroll
    for (int mt = 0; mt < 4; mt++) {
#pragma unroll
        for (int p = 0; p < 2; p++) {
            float s22 = 0, s24 = 0, s42 = 0, s44 = 0;
#pragma unroll
            for (int nt = 0; nt < 2; nt++) {
                float q0 = qa[mt][nt][2 * p] + bqv2[nt];
                float q1 = qa[mt][nt][2 * p + 1] + bqv2[nt];
                float k0v = ka[mt][nt][2 * p] + bkv2[nt];
                float k1v = ka[mt][nt][2 * p + 1] + bkv2[nt];
                s22 += q0 * k0v; s24 += q0 * k1v; s42 += q1 * k0v; s44 += q1 * k1v;
            }
#pragma unroll
            for (int d = 1; d < 16; d <<= 1) {
                s22 += __shfl_xor(s22, d, 64);
                s24 += __shfl_xor(s24, d, 64);
                s42 += __shfl_xor(s42, d, 64);
                s44 += __shfl_xor(s44, d, 64);
            }
            if (l15 == 0) {
                const int i = (m0 + wm + mt * 16 + quad * 4 + 2 * p) >> 1;
                floatx4 v;
                v[0] = s22; v[1] = s24; v[2] = s42; v[3] = s44;
                sp[(size_t)bx * B_N + i] = v;
            }
        }
    }
}

// ---------- fused: partial-reduce + softmax -> gamma; in-place z-combine ----------
__global__ __launch_bounds__(256) void k_zgam(unsigned short* __restrict__ tok,
                                              const floatx4* __restrict__ sp) {
    __shared__ floatx4 lg[2];
    const int b = blockIdx.x;   // B_N/2 blocks, 2 pair-rows each
    const int t = threadIdx.x;
    if (t < 2) {
        const int i = b * 2 + t;
        float a[8];
#pragma unroll
        for (int j = 0; j < 8; j++) a[j] = 0.0f;
#pragma unroll
        for (int q = 0; q < 16; q++) {
            floatx4 v = sp[(size_t)q * B_N + i];
            const int h4 = (q >> 3) * 4;
            a[h4 + 0] += v[0]; a[h4 + 1] += v[1]; a[h4 + 2] += v[2]; a[h4 + 3] += v[3];
        }
        const float sc = 0.044194173824159216f;  // 1/sqrt(512)
        floatx4 g;
#pragma unroll
        for (int h = 0; h < 2; h++) {
            float s22 = a[h * 4 + 0] * sc, s24 = a[h * 4 + 1] * sc;
            float s42 = a[h * 4 + 2] * sc, s44 = a[h * 4 + 3] * sc;
            float m0 = fmaxf(s22, s24), e22 = __expf(s22 - m0), e24 = __expf(s24 - m0);
            float w24 = e24 / (e22 + e24), w22 = 1.0f - w24;
            float m1 = fmaxf(s42, s44), e42 = __expf(s42 - m1), e44 = __expf(s44 - m1);
            float w44 = e44 / (e42 + e44), w42 = 1.0f - w44;
            g[h * 2 + 0] = 0.5f * (w22 + w42);
            g[h * 2 + 1] = 0.5f * (w24 + w44);
        }
        lg[t] = g;
    }
    __syncthreads();
    const int i = b * 2 + (t >> 7);
    const int seg = (t & 127) * 8;
    floatx4 g = lg[t >> 7];
    short8 a = *(const short8*)(tok + (size_t)(2 * i) * D_DIM + seg);
    short8 bb = *(const short8*)(tok + (size_t)(2 * i + 1) * D_DIM + seg);
    ushort8 z1, z2;
#pragma unroll
    for (int j = 0; j < 8; j++) {
        float af = bf2f((unsigned short)a[j]), bf = bf2f((unsigned short)bb[j]);
        z1[j] = f2bf(g[0] * af + g[1] * bf);
        z2[j] = f2bf(g[2] * af + g[3] * bf);
    }
    *(ushort8*)(tok + (size_t)(2 * i) * D_DIM + seg) = z1;
    *(ushort8*)(tok + (size_t)(2 * i + 1) * D_DIM + seg) = z2;
}

extern "C" void kernel_launch(void* const* d_in, const int* in_sizes, int n_in,
                              void* d_out, int out_size, void* d_ws, size_t ws_size,
                              hipStream_t stream) {
    const float* x = (const float*)d_in[0];
    const int* labels = (const int*)d_in[1];
    const float* conv_w2 = (const float*)d_in[3];
    const float* conv_b2 = (const float*)d_in[4];
    const float* conv_w4 = (const float*)d_in[5];
    const float* conv_b4 = (const float*)d_in[6];
    const float* intra_in_w = (const float*)d_in[7];
    const float* intra_in_b = (const float*)d_in[8];
    const float* intra_out_w = (const float*)d_in[9];
    const float* intra_out_b = (const float*)d_in[10];
    const float* inter_in_w = (const float*)d_in[11];
    const float* inter_in_b = (const float*)d_in[12];
    const float* inter_out_w = (const float*)d_in[13];
    const float* inter_out_b = (const float*)d_in[14];
    const float* lin_w = (const float*)d_in[15];
    const float* lin_b = (const float*)d_in[16];
    float* out = (float*)d_out;

    char* p = (char*)d_ws;
    auto alloc = [&](size_t bytes) -> void* {
        void* r = (void*)p;
        p += (bytes + 255) & ~(size_t)255;
        return r;
    };
    int* perm = (int*)alloc(B_N * 4);
    int* lss = (int*)alloc(B_N * 4);
    int* hist = (int*)alloc(NCHUNK * NGRP * 4);
    int* gstart = (int*)alloc((NGRP + 1) * 4);
    int* counts = (int*)alloc(NGRP * 4);
    float* scal = (float*)alloc(4);
    unsigned short* tok = (unsigned short*)alloc((size_t)2 * B_N * D_DIM * 2);   // 64 MB
    unsigned short* Wqk = (unsigned short*)alloc((size_t)2 * D_DIM * D_DIM * 2); // 4 MB
    unsigned short* linwb = (unsigned short*)alloc((size_t)D_DIM * D_DIM * 2);
    unsigned short* WoT = (unsigned short*)alloc((size_t)D_DIM * D_DIM * 2);
    unsigned short* WvT = (unsigned short*)alloc((size_t)D_DIM * D_DIM * 2);
    unsigned short* Wc = (unsigned short*)alloc((size_t)D_DIM * D_DIM * 2);
    unsigned short* GG = (unsigned short*)alloc((size_t)D_DIM * 2 * D_DIM * 2);  // 4 MB
    floatx4* sp = (floatx4*)alloc((size_t)16 * B_N * 16);                        // 4 MB
    float* u = (float*)alloc((size_t)NGRP * D_DIM * 4);
    float* fbuf = (float*)alloc((size_t)NGRP * D_DIM * 4);
    float* imean = (float*)alloc((size_t)NGRP * D_DIM * 4);
    float* biasc = (float*)alloc(D_DIM * 4);
    float* ob2 = (float*)alloc(D_DIM * 4);

    // ---- sort ----
    k_hist<<<NCHUNK, CHUNK, 0, stream>>>(labels, hist);
    k_scan<<<1, NGRP, 0, stream>>>(hist, gstart, counts, scal);
    k_scatter<<<NCHUNK, CHUNK, 0, stream>>>(labels, hist, perm, lss);
    // ---- weight prep (casts + transposes + ob2 in one dispatch) ----
    k_prep<<<5124, 256, 0, stream>>>(intra_in_w, lin_w, intra_out_w, intra_out_b, Wqk,
                                     linwb, WoT, WvT, intra_in_b + 2 * D_DIM, ob2);
    gemm_bt<1><<<dim3(8, 8), 256, 0, stream>>>(linwb, WoT, 1024, 1024, 1024, 1024, 1024,
                                               nullptr, Wc, 1024, nullptr, nullptr,
                                               nullptr, nullptr);
    // GG[n][h*1024+k] = sum_e Wc[n][h*512+e] * WvT[k][h*512+e]  (both heads, one dispatch)
    gemm_bt<3><<<dim3(16, 8), 256, 0, stream>>>(Wc, WvT, 1024, 2048, 512, 1024, 1024,
                                                nullptr, GG, 2048, nullptr, nullptr,
                                                nullptr, nullptr);
    // ---- inter path (fp32) + biasc ----
    k_u<<<dim3(4, NGRP + 1), 256, 0, stream>>>(x, perm, gstart, counts, inter_in_w,
                                               inter_in_b, u, lin_w, lin_b, ob2, biasc);
    k_f<<<dim3(4, NGRP), 256, 0, stream>>>(u, counts, inter_out_w, inter_out_b, fbuf);
    k_imean<<<4, 256, 0, stream>>>(fbuf, scal, imean);
    // ---- conv -> interleaved tok (4 rows/block) ----
    k_conv<<<B_N / 4, 256, 0, stream>>>(x, perm, lss, conv_w2, conv_b2, conv_w4, conv_b4,
                                        tok);
    // ---- fused qk + score partials ----
    k_qkscore<<<dim3(16, 256), 256, 0, stream>>>(tok, Wqk, Wqk + (size_t)D_DIM * D_DIM,
                                                 intra_in_b, intra_in_b + D_DIM, sp);
    // ---- gamma + in-place z-combine ----
    k_zgam<<<B_N / 2, 256, 0, stream>>>(tok, sp);
    // ---- merged v+out GEMM: out[perm[i]] = [z1|z2] . GG^T + biasc + imean ----
    gemm_bt<2><<<dim3(8, 128), 256, 0, stream>>>(tok, GG, B_N, 1024, 2048, 2048, 2048,
                                                 biasc, nullptr, 0, out, perm, lss, imean);
}